// Round 13
// baseline (105.673 us; speedup 1.0000x reference)
//
#include <hip/hip_runtime.h>
#include <hip/hip_bf16.h>
#include <math.h>

#define IN_FEAT 4096
#define OUT_FEAT 4096
#define NCOMP 256
#define BATCH 4096
#define TWO_PI_F 6.28318530717958647692f

typedef __attribute__((ext_vector_type(8))) short short8;
typedef __attribute__((ext_vector_type(8))) __bf16 bf16x8;
typedef __attribute__((ext_vector_type(4))) float f32x4;
typedef __attribute__((ext_vector_type(16))) float f32x16;

// round-to-nearest-even f32 -> bf16
__device__ __forceinline__ ushort f2b(float f) {
  union { float f; unsigned u; } v; v.f = f;
  unsigned r = (v.u + 0x7fffu + ((v.u >> 16) & 1u)) >> 16;
  return (ushort)r;
}

__device__ __forceinline__ bf16x8 ld_frag(const void* p) {
  short8 s = *(const short8*)p;
  return __builtin_bit_cast(bf16x8, s);
}

// native casts -> v_cvt_pk_bf16_f32 (RTNE)
__device__ __forceinline__ short8 cvt8s(float4 a, float4 b) {
  bf16x8 r;
  r[0] = (__bf16)a.x; r[1] = (__bf16)a.y; r[2] = (__bf16)a.z; r[3] = (__bf16)a.w;
  r[4] = (__bf16)b.x; r[5] = (__bf16)b.y; r[6] = (__bf16)b.z; r[7] = (__bf16)b.w;
  return __builtin_bit_cast(short8, r);
}

__device__ __forceinline__ void gload_lds16(const void* g, void* l) {
  __builtin_amdgcn_global_load_lds(
      (const __attribute__((address_space(1))) void*)g,
      (__attribute__((address_space(3))) void*)l, 16, 0, 0);
}

// ---------------------------------------------------------------- prep
__global__ __launch_bounds__(256) void prep_kernel(
    const float* __restrict__ mus, const float* __restrict__ lvs,
    const float* __restrict__ w,
    ushort* __restrict__ Gt, ushort* __restrict__ GoT) {
  int idx = blockIdx.x * 256 + threadIdx.x;
  if (idx < NCOMP * IN_FEAT) {
    int m = idx >> 12, i = idx & (IN_FEAT - 1);
    float v = expf(lvs[2 * m]);
    float d = (float)i * (1.0f / (IN_FEAT - 1)) - mus[2 * m];
    float g = expf(-d * d * (0.5f / v)) * rsqrtf(TWO_PI_F * v) * w[m];
    Gt[idx] = f2b(g);
  } else {
    idx -= NCOMP * IN_FEAT;
    int o = idx >> 8, m = idx & (NCOMP - 1);
    float v = expf(lvs[2 * m + 1]);
    float d = (float)o * (1.0f / (OUT_FEAT - 1)) - mus[2 * m + 1];
    float g = expf(-d * d * (0.5f / v)) * rsqrtf(TWO_PI_F * v);
    GoT[idx] = f2b(g);
  }
}

// ---------------------------------------------------------------- GEMM1
// Row-contiguous, single-pass: Cb[4096][256](bf16) = x @ Gt^T.
// Block = 16 batch rows x FULL K=4096 (no split-K, no partials, no reduce).
// x[16][4096] staged to LDS as bf16 (128 KB) in 4 chunks of 1024k, each
// read as ~1KB-contiguous row segments (DRAM-page friendly) and
// issue-early/write-late overlapped with the previous chunk's compute.
// Phase 1: 8 waves split N (wave = 16 rows x 32 cols, all K): A from
// swizzled LDS (2-way max), B = 2 dwordx4/step from L2-resident Gt with
// depth-4 register prefetch, 2 MFMA/step. Grid 256 blocks = 1/CU.
__global__ __launch_bounds__(512, 2) void gemm1_kernel(
    const float* __restrict__ x, const ushort* __restrict__ Gt,
    ushort* __restrict__ Cb) {
  __shared__ __align__(16) ushort xs[16 * 4096];  // 128 KB bf16 [row][k]
  const int tid = threadIdx.x, wid = tid >> 6, lane = tid & 63;
  const int l15 = lane & 15, q = lane >> 4;
  const int m0 = blockIdx.x * 16;

  // staging: thread -> row=tid>>5, c=tid&31; chunk = 1024 k (128 slots/row)
  const int srow = tid >> 5, sc = tid & 31;
  const float* xsrc = &x[(size_t)(m0 + srow) * IN_FEAT];
  const int sbase = srow * 8192;            // byte base of row in xs
  const int sswz = (srow & 7) << 4;         // row-XOR swizzle

  #define ISSUE(c, F)                                                        \
    _Pragma("unroll")                                                        \
    for (int j = 0; j < 4; ++j) {                                            \
      int s = (c) * 128 + j * 32 + sc;                                       \
      F[2 * j]     = *(const float4*)(xsrc + s * 8);                         \
      F[2 * j + 1] = *(const float4*)(xsrc + s * 8 + 4);                     \
    }

  #define WRITE(c, F)                                                        \
    _Pragma("unroll")                                                        \
    for (int j = 0; j < 4; ++j) {                                            \
      int s = (c) * 128 + j * 32 + sc;                                       \
      *(short8*)((char*)xs + ((sbase + s * 16) ^ sswz)) =                    \
          cvt8s(F[2 * j], F[2 * j + 1]);                                     \
    }

  // phase-1 per-wave setup: n-slice = wid*32
  const int nw = wid * 32;
  const ushort* gb0 = &Gt[(size_t)(nw + l15) * IN_FEAT + q * 8];
  const ushort* gb1 = gb0 + (size_t)16 * IN_FEAT;
  const int abyte0 = l15 * 8192 + q * 16;   // + t*64, then ^ swz
  const int aswz = (l15 & 7) << 4;

  f32x4 acc[2] = {};
  short8 P[4][2];

  // chunk 0 staged synchronously; B prefetch t=0..3 issued alongside
  {
    float4 F[8];
    ISSUE(0, F)
    #pragma unroll
    for (int t = 0; t < 4; ++t) {
      P[t][0] = *(const short8*)(gb0 + t * 32);
      P[t][1] = *(const short8*)(gb1 + t * 32);
    }
    WRITE(0, F)
  }
  __syncthreads();

  for (int c = 0; c < 4; ++c) {
    float4 Fn[8];
    if (c < 3) ISSUE(c + 1, Fn)          // overlap next chunk's x loads
    #pragma unroll 4
    for (int u = 0; u < 32; ++u) {
      const int t = c * 32 + u;
      bf16x8 a = ld_frag((const char*)xs + ((abyte0 + t * 64) ^ aswz));
      bf16x8 b0 = __builtin_bit_cast(bf16x8, P[u & 3][0]);
      bf16x8 b1 = __builtin_bit_cast(bf16x8, P[u & 3][1]);
      if (t + 4 < 128) {                 // reload this slot 4 steps ahead
        P[u & 3][0] = *(const short8*)(gb0 + (t + 4) * 32);
        P[u & 3][1] = *(const short8*)(gb1 + (t + 4) * 32);
      }
      acc[0] = __builtin_amdgcn_mfma_f32_16x16x32_bf16(a, b0, acc[0], 0, 0, 0);
      acc[1] = __builtin_amdgcn_mfma_f32_16x16x32_bf16(a, b1, acc[1], 0, 0, 0);
    }
    if (c < 3) { WRITE(c + 1, Fn) }      // write-late: after compute
    __syncthreads();
  }
  #undef ISSUE
  #undef WRITE

  #pragma unroll
  for (int j = 0; j < 2; ++j)
    #pragma unroll
    for (int r = 0; r < 4; ++r)
      Cb[(size_t)(m0 + q * 4 + r) * NCOMP + nw + j * 16 + l15] =
          f2b(acc[j][r]);
}

// ---------------------------------------------------------------- GEMM2
// out[4096][4096](f32) = (Cb @ GoT^T) * scale; 32x32x16 MFMA.
// BM=BN=128; wave owns 64x64 (2x2 frags). Stage=32k, dbuf 32 KB.
__global__ __launch_bounds__(256, 4) void gemm2_kernel(
    const ushort* __restrict__ Cb, const ushort* __restrict__ GoT,
    const float* __restrict__ w, float* __restrict__ out) {
  __shared__ __align__(16) ushort lds[2 * 8192];  // per buf: A 8 KB, B 8 KB
  const int tid = threadIdx.x, wid = tid >> 6, lane = tid & 63;
  const int m0 = blockIdx.y * 128, n0 = blockIdx.x * 128;
  const int wr = (wid >> 1) * 64, wc = (wid & 1) * 64;
  const int r32 = lane & 31, h = lane >> 5;

  float4 wv = *(const float4*)&w[lane * 4];
  float s = wv.x + wv.y + wv.z + wv.w;
  #pragma unroll
  for (int off = 32; off > 0; off >>= 1) s += __shfl_xor(s, off);
  const float scale = 1.0f / ((float)IN_FEAT * s);

  const int brow = lane >> 2;
  const int bswz = (((lane & 3) ^ ((lane >> 3) & 3)) << 3);
  const int sw0 = (h << 4) ^ (((r32 >> 1) & 3) << 4);

  f32x16 acc[2][2] = {};

  #define STAGE2(buf, k0)                                                    \
    _Pragma("unroll")                                                        \
    for (int q2 = 0; q2 < 2; ++q2) {                                         \
      int c = wid * 2 + q2;                                                  \
      int row = c * 16 + brow;                                               \
      gload_lds16(&Cb[(size_t)(m0 + row) * NCOMP + (k0) + bswz],             \
                  &lds[(buf) * 8192 + c * 512]);                             \
      gload_lds16(&GoT[(size_t)(n0 + row) * NCOMP + (k0) + bswz],            \
                  &lds[(buf) * 8192 + 4096 + c * 512]);                      \
    }

  STAGE2(0, 0)
  __syncthreads();

  for (int t = 0; t < 8; ++t) {
    if (t < 7) STAGE2((t + 1) & 1, (t + 1) * 32)
    const char* base = (const char*)lds + (t & 1) * 16384;
    const char* Bb = base + 8192;
    #pragma unroll
    for (int s2 = 0; s2 < 2; ++s2) {
      const int off = sw0 ^ (s2 << 5);
      bf16x8 a0 = ld_frag(base + (wr + r32) * 64 + off);
      bf16x8 a1 = ld_frag(base + (wr + 32 + r32) * 64 + off);
      bf16x8 b0 = ld_frag(Bb + (wc + r32) * 64 + off);
      bf16x8 b1 = ld_frag(Bb + (wc + 32 + r32) * 64 + off);
      acc[0][0] = __builtin_amdgcn_mfma_f32_32x32x16_bf16(a0, b0, acc[0][0], 0, 0, 0);
      acc[0][1] = __builtin_amdgcn_mfma_f32_32x32x16_bf16(a0, b1, acc[0][1], 0, 0, 0);
      acc[1][0] = __builtin_amdgcn_mfma_f32_32x32x16_bf16(a1, b0, acc[1][0], 0, 0, 0);
      acc[1][1] = __builtin_amdgcn_mfma_f32_32x32x16_bf16(a1, b1, acc[1][1], 0, 0, 0);
    }
    __syncthreads();
  }
  #undef STAGE2

  #pragma unroll
  for (int mi = 0; mi < 2; ++mi)
    #pragma unroll
    for (int nj = 0; nj < 2; ++nj)
      #pragma unroll
      for (int g = 0; g < 16; ++g) {
        int row = m0 + wr + mi * 32 + (g & 3) + 8 * (g >> 2) + 4 * h;
        int col = n0 + wc + nj * 32 + r32;
        out[(size_t)row * OUT_FEAT + col] = acc[mi][nj][g] * scale;
      }
}

// ---------------------------------------------------------------- launch
extern "C" void kernel_launch(void* const* d_in, const int* in_sizes, int n_in,
                              void* d_out, int out_size, void* d_ws, size_t ws_size,
                              hipStream_t stream) {
  const float* x   = (const float*)d_in[0];
  const float* mus = (const float*)d_in[1];
  const float* lvs = (const float*)d_in[2];
  const float* w   = (const float*)d_in[3];
  float* out = (float*)d_out;

  ushort* Gt  = (ushort*)d_ws;                      // [256][4096] bf16, 2 MiB
  ushort* GoT = Gt  + (size_t)NCOMP * IN_FEAT;      // [4096][256] bf16, 2 MiB
  ushort* Cb  = GoT + (size_t)OUT_FEAT * NCOMP;     // [4096][256] bf16, 2 MiB

  prep_kernel<<<(NCOMP * IN_FEAT + OUT_FEAT * NCOMP) / 256, 256, 0, stream>>>(
      mus, lvs, w, Gt, GoT);

  gemm1_kernel<<<BATCH / 16, 512, 0, stream>>>(x, Gt, Cb);

  gemm2_kernel<<<dim3(OUT_FEAT / 128, BATCH / 128), 256, 0, stream>>>(
      Cb, GoT, w, out);
}

// Round 14
// 61.326 us; speedup vs baseline: 1.7231x; 1.7231x over previous
//
#include <hip/hip_runtime.h>
#include <hip/hip_bf16.h>
#include <math.h>

#define IN_FEAT 4096
#define OUT_FEAT 4096
#define NCOMP 256
#define BATCH 4096
#define TWO_PI_F 6.28318530717958647692f

typedef __attribute__((ext_vector_type(8))) short short8;
typedef __attribute__((ext_vector_type(8))) __bf16 bf16x8;
typedef __attribute__((ext_vector_type(4))) float f32x4;
typedef __attribute__((ext_vector_type(16))) float f32x16;

// round-to-nearest-even f32 -> bf16
__device__ __forceinline__ ushort f2b(float f) {
  union { float f; unsigned u; } v; v.f = f;
  unsigned r = (v.u + 0x7fffu + ((v.u >> 16) & 1u)) >> 16;
  return (ushort)r;
}

__device__ __forceinline__ float b2f(short s) {
  union { unsigned u; float f; } v; v.u = ((unsigned)(ushort)s) << 16;
  return v.f;
}

__device__ __forceinline__ bf16x8 ld_frag(const void* p) {
  short8 s = *(const short8*)p;
  return __builtin_bit_cast(bf16x8, s);
}

// native casts -> v_cvt_pk_bf16_f32 (RTNE)
__device__ __forceinline__ bf16x8 cvt8f(float4 a, float4 b) {
  bf16x8 r;
  r[0] = (__bf16)a.x; r[1] = (__bf16)a.y; r[2] = (__bf16)a.z; r[3] = (__bf16)a.w;
  r[4] = (__bf16)b.x; r[5] = (__bf16)b.y; r[6] = (__bf16)b.z; r[7] = (__bf16)b.w;
  return r;
}

__device__ __forceinline__ void gload_lds16(const void* g, void* l) {
  __builtin_amdgcn_global_load_lds(
      (const __attribute__((address_space(1))) void*)g,
      (__attribute__((address_space(3))) void*)l, 16, 0, 0);
}

// ---------------------------------------------------------------- prep
__global__ __launch_bounds__(256) void prep_kernel(
    const float* __restrict__ mus, const float* __restrict__ lvs,
    const float* __restrict__ w,
    ushort* __restrict__ Gt, ushort* __restrict__ GoT) {
  int idx = blockIdx.x * 256 + threadIdx.x;
  if (idx < NCOMP * IN_FEAT) {
    int m = idx >> 12, i = idx & (IN_FEAT - 1);
    float v = expf(lvs[2 * m]);
    float d = (float)i * (1.0f / (IN_FEAT - 1)) - mus[2 * m];
    float g = expf(-d * d * (0.5f / v)) * rsqrtf(TWO_PI_F * v) * w[m];
    Gt[idx] = f2b(g);
  } else {
    idx -= NCOMP * IN_FEAT;
    int o = idx >> 8, m = idx & (NCOMP - 1);
    float v = expf(lvs[2 * m + 1]);
    float d = (float)o * (1.0f / (OUT_FEAT - 1)) - mus[2 * m + 1];
    float g = expf(-d * d * (0.5f / v)) * rsqrtf(TWO_PI_F * v);
    GoT[idx] = f2b(g);
  }
}

// ---------------------------------------------------------------- GEMM1
// R12's persistent-B loop + in-block k-chunking (NSPLIT=4 instead of 16).
// Block = 64 rows x 256 cols x KR=1024 k. Per 256-k sub-chunk: re-stage the
// full 256n x 256k B panel (128 KB LDS) via gload_lds (wave w stages seg w),
// then 8 barrier-free steps: A from x via depth-4 rotating register prefetch
// (1 KB/row granule), B via verified-conflict-free swizzled ds_read_b128,
// 8 MFMA/step. acc persists across sub-chunks -> partial traffic /4.
// Raw s_barrier + counted vmcnt(8) at restage (NOT __syncthreads: that
// drains vmcnt(0) and kills the x pipeline). Grid (64, NSPLIT) = 256 blocks.
template<int NSPLIT>
__global__ __launch_bounds__(512, 2) void gemm1_kernel(
    const float* __restrict__ x, const ushort* __restrict__ Gt,
    ushort* __restrict__ Cpart) {
  constexpr int KR = IN_FEAT / NSPLIT;
  constexpr int NSC = KR / 256;  // sub-chunks per block
  __shared__ __align__(16) ushort Bs[8 * 8192];  // 128 KB
  const int tid = threadIdx.x, wid = tid >> 6, lane = tid & 63;
  const int l15 = lane & 15, q = lane >> 4;
  const int rg = wid >> 1, h2 = wid & 1;  // row-group 0..3, n-half 0..1
  const int m0 = blockIdx.x * 64;
  const int kb0 = blockIdx.y * KR;

  // B staging: wave stages seg wid; 16 col-chunks (16 rows x 64 B each)
  const int brow = lane >> 2;
  const int bsw = (((lane & 3) ^ ((lane >> 3) & 3)) << 3);  // ushort units
  // fragment-read swizzle (pairs with bsw; measured 0 conflicts R11/R12)
  const int fswz = (q << 4) ^ (((l15 >> 1) & 3) << 4);

  const float* xa = &x[(size_t)(m0 + rg * 16 + l15) * IN_FEAT + kb0 + q * 8];

  f32x4 acc[8] = {};
  float4 P[4][2];

  for (int kc = 0; kc < NSC; ++kc) {
    if (kc) __builtin_amdgcn_s_barrier();  // all waves done with old panel
    // stage B panel for this sub-chunk (16 gload_lds per wave)
    #pragma unroll
    for (int nf = 0; nf < 16; ++nf)
      gload_lds16(
          &Gt[(size_t)(nf * 16 + brow) * IN_FEAT + kb0 + kc * 256 + wid * 32 + bsw],
          &Bs[wid * 8192 + nf * 512]);
    __builtin_amdgcn_sched_barrier(0);  // pin: B DMAs before P loads
    const float* xk = xa + kc * 256;
    #pragma unroll
    for (int s = 0; s < 4; ++s) {
      P[s][0] = *(const float4*)(xk + s * 32);
      P[s][1] = *(const float4*)(xk + s * 32 + 4);
    }
    // wait the 16 B DMAs (oldest); the 8 P loads stay in flight
    asm volatile("s_waitcnt vmcnt(8)" ::: "memory");
    __builtin_amdgcn_s_barrier();
    __builtin_amdgcn_sched_barrier(0);

    #pragma unroll
    for (int t = 0; t < 8; ++t) {
      bf16x8 a = cvt8f(P[t & 3][0], P[t & 3][1]);
      if (t < 4) {  // reload this slot 4 steps ahead (issues under MFMAs)
        P[t][0] = *(const float4*)(xk + (t + 4) * 32);
        P[t][1] = *(const float4*)(xk + (t + 4) * 32 + 4);
      }
      const char* sb = (const char*)Bs + t * 16384;
      #pragma unroll
      for (int j = 0; j < 8; ++j) {
        bf16x8 b = ld_frag(sb + ((h2 * 8 + j) * 16 + l15) * 64 + fswz);
        acc[j] = __builtin_amdgcn_mfma_f32_16x16x32_bf16(a, b, acc[j], 0, 0, 0);
      }
    }
  }

  ushort* Cp = Cpart + (size_t)blockIdx.y * ((size_t)BATCH * NCOMP);
  #pragma unroll
  for (int j = 0; j < 8; ++j)
    #pragma unroll
    for (int r = 0; r < 4; ++r) {
      int row = m0 + rg * 16 + q * 4 + r;
      int col = h2 * 128 + j * 16 + l15;
      Cp[(size_t)row * NCOMP + col] = f2b(acc[j][r]);
    }
}

// ---------------------------------------------------------------- reduce
template<int NS>
__global__ __launch_bounds__(256) void reduce_kernel(ushort* __restrict__ Cp) {
  size_t i = ((size_t)blockIdx.x * 256 + threadIdx.x) * 8;
  float s[8] = {};
  #pragma unroll
  for (int p = 0; p < NS; ++p) {
    short8 v = *(const short8*)&Cp[(size_t)p * BATCH * NCOMP + i];
    #pragma unroll
    for (int e = 0; e < 8; ++e) s[e] += b2f(v[e]);
  }
  short8 hh;
  #pragma unroll
  for (int e = 0; e < 8; ++e) hh[e] = (short)f2b(s[e]);
  *(short8*)&Cp[i] = hh;
}

// ---------------------------------------------------------------- GEMM2
// out[4096][4096](f32) = (Cb @ GoT^T) * scale; 32x32x16 MFMA.
// BM=BN=128; wave owns 64x64 (2x2 frags). Stage=32k, dbuf 32 KB.
__global__ __launch_bounds__(256, 4) void gemm2_kernel(
    const ushort* __restrict__ Cb, const ushort* __restrict__ GoT,
    const float* __restrict__ w, float* __restrict__ out) {
  __shared__ __align__(16) ushort lds[2 * 8192];  // per buf: A 8 KB, B 8 KB
  const int tid = threadIdx.x, wid = tid >> 6, lane = tid & 63;
  const int m0 = blockIdx.y * 128, n0 = blockIdx.x * 128;
  const int wr = (wid >> 1) * 64, wc = (wid & 1) * 64;
  const int r32 = lane & 31, h = lane >> 5;

  float4 wv = *(const float4*)&w[lane * 4];
  float s = wv.x + wv.y + wv.z + wv.w;
  #pragma unroll
  for (int off = 32; off > 0; off >>= 1) s += __shfl_xor(s, off);
  const float scale = 1.0f / ((float)IN_FEAT * s);

  const int brow = lane >> 2;
  const int bswz = (((lane & 3) ^ ((lane >> 3) & 3)) << 3);
  const int sw0 = (h << 4) ^ (((r32 >> 1) & 3) << 4);

  f32x16 acc[2][2] = {};

  #define STAGE2(buf, k0)                                                    \
    _Pragma("unroll")                                                        \
    for (int q2 = 0; q2 < 2; ++q2) {                                         \
      int c = wid * 2 + q2;                                                  \
      int row = c * 16 + brow;                                               \
      gload_lds16(&Cb[(size_t)(m0 + row) * NCOMP + (k0) + bswz],             \
                  &lds[(buf) * 8192 + c * 512]);                             \
      gload_lds16(&GoT[(size_t)(n0 + row) * NCOMP + (k0) + bswz],            \
                  &lds[(buf) * 8192 + 4096 + c * 512]);                      \
    }

  STAGE2(0, 0)
  __syncthreads();

  for (int t = 0; t < 8; ++t) {
    if (t < 7) STAGE2((t + 1) & 1, (t + 1) * 32)
    const char* base = (const char*)lds + (t & 1) * 16384;
    const char* Bb = base + 8192;
    #pragma unroll
    for (int s2 = 0; s2 < 2; ++s2) {
      const int off = sw0 ^ (s2 << 5);
      bf16x8 a0 = ld_frag(base + (wr + r32) * 64 + off);
      bf16x8 a1 = ld_frag(base + (wr + 32 + r32) * 64 + off);
      bf16x8 b0 = ld_frag(Bb + (wc + r32) * 64 + off);
      bf16x8 b1 = ld_frag(Bb + (wc + 32 + r32) * 64 + off);
      acc[0][0] = __builtin_amdgcn_mfma_f32_32x32x16_bf16(a0, b0, acc[0][0], 0, 0, 0);
      acc[0][1] = __builtin_amdgcn_mfma_f32_32x32x16_bf16(a0, b1, acc[0][1], 0, 0, 0);
      acc[1][0] = __builtin_amdgcn_mfma_f32_32x32x16_bf16(a1, b0, acc[1][0], 0, 0, 0);
      acc[1][1] = __builtin_amdgcn_mfma_f32_32x32x16_bf16(a1, b1, acc[1][1], 0, 0, 0);
    }
    __syncthreads();
  }
  #undef STAGE2

  #pragma unroll
  for (int mi = 0; mi < 2; ++mi)
    #pragma unroll
    for (int nj = 0; nj < 2; ++nj)
      #pragma unroll
      for (int g = 0; g < 16; ++g) {
        int row = m0 + wr + mi * 32 + (g & 3) + 8 * (g >> 2) + 4 * h;
        int col = n0 + wc + nj * 32 + r32;
        out[(size_t)row * OUT_FEAT + col] = acc[mi][nj][g] * scale;
      }
}

// ---------------------------------------------------------------- launch
extern "C" void kernel_launch(void* const* d_in, const int* in_sizes, int n_in,
                              void* d_out, int out_size, void* d_ws, size_t ws_size,
                              hipStream_t stream) {
  const float* x   = (const float*)d_in[0];
  const float* mus = (const float*)d_in[1];
  const float* lvs = (const float*)d_in[2];
  const float* w   = (const float*)d_in[3];
  float* out = (float*)d_out;

  ushort* Gt  = (ushort*)d_ws;                      // [256][4096] bf16, 2 MiB
  ushort* GoT = Gt  + (size_t)NCOMP * IN_FEAT;      // [4096][256] bf16, 2 MiB
  ushort* Cpart = GoT + (size_t)OUT_FEAT * NCOMP;   // 4 x 2 MiB; Cb = Cpart[0]

  const size_t MiB = 1024 * 1024;
  const bool split4 = ws_size >= 14 * MiB;

  prep_kernel<<<(NCOMP * IN_FEAT + OUT_FEAT * NCOMP) / 256, 256, 0, stream>>>(
      mus, lvs, w, Gt, GoT);

  if (split4) {
    gemm1_kernel<4><<<dim3(BATCH / 64, 4), 512, 0, stream>>>(x, Gt, Cpart);
    reduce_kernel<4><<<BATCH * NCOMP / 8 / 256, 256, 0, stream>>>(Cpart);
  } else {
    gemm1_kernel<1><<<dim3(BATCH / 64, 1), 512, 0, stream>>>(x, Gt, Cpart);
  }

  gemm2_kernel<<<dim3(OUT_FEAT / 128, BATCH / 128), 256, 0, stream>>>(
      Cpart, GoT, w, out);
}